// Round 4
// baseline (351.542 us; speedup 1.0000x reference)
//
#include <hip/hip_runtime.h>
#include <hip/hip_bf16.h>

#define N_NODE  50000
#define N_PAD   50048   // buffer row count (391*128); M-tiles of 256 cover 50176 w/ clamp+guard
#define N_GRAPH 1024
#define DD      512
#define BKT     32
#define NKT     16      // 512 / 32

typedef __attribute__((ext_vector_type(8))) short bf16x8;
typedef __attribute__((ext_vector_type(4))) float f32x4;

__device__ __forceinline__ unsigned short f2bf(float f) {
  unsigned int u = __builtin_bit_cast(unsigned int, f);
  return (unsigned short)((u + 0x7FFFu + ((u >> 16) & 1u)) >> 16);  // RTN-even
}

__device__ __forceinline__ float bf2f(unsigned short h) {
  unsigned int u = ((unsigned int)h) << 16;
  return __builtin_bit_cast(float, u);
}

__device__ __forceinline__ void gload16(const void* g, void* l) {
  __builtin_amdgcn_global_load_lds(
      (const __attribute__((address_space(1))) unsigned int*)g,
      (__attribute__((address_space(3))) unsigned int*)l, 16, 0, 0);
}

// T1: bijective XCD-chunk remap (m204 variant)
__device__ __forceinline__ int xcd_remap(int bid, int nwg) {
  int xcd = bid & 7;
  int local = bid >> 3;
  int q = nwg >> 3, r = nwg & 7;
  int base = (xcd < r) ? xcd * (q + 1) : r * (q + 1) + (xcd - r) * q;
  return base + local;
}

// ---- cast kernels -----------------------------------------------------------

__global__ void cast_pad_kernel(const float* __restrict__ src,
                                unsigned short* __restrict__ dst,
                                int srcRows, int dstRows) {
  long long base = ((long long)blockIdx.x * blockDim.x + threadIdx.x) * 8;
  if (base >= (long long)dstRows * DD) return;
  int row = (int)(base >> 9);
  bf16x8 o;
  if (row < srcRows) {
    float4 x0 = reinterpret_cast<const float4*>(src + base)[0];
    float4 x1 = reinterpret_cast<const float4*>(src + base)[1];
    o[0] = (short)f2bf(x0.x); o[1] = (short)f2bf(x0.y);
    o[2] = (short)f2bf(x0.z); o[3] = (short)f2bf(x0.w);
    o[4] = (short)f2bf(x1.x); o[5] = (short)f2bf(x1.y);
    o[6] = (short)f2bf(x1.z); o[7] = (short)f2bf(x1.w);
  } else {
    for (int i = 0; i < 8; ++i) o[i] = 0;
  }
  *reinterpret_cast<bf16x8*>(dst + base) = o;
}

struct WPtrs { const float* p[8]; };

__global__ void cast_w_kernel(WPtrs ps, unsigned short* __restrict__ dst) {
  long long base = ((long long)blockIdx.x * blockDim.x + threadIdx.x) * 8;
  int mat = (int)(base >> 18);
  int off = (int)(base & 262143LL);
  const float* s = ps.p[mat] + off;
  float4 x0 = reinterpret_cast<const float4*>(s)[0];
  float4 x1 = reinterpret_cast<const float4*>(s)[1];
  bf16x8 o;
  o[0] = (short)f2bf(x0.x); o[1] = (short)f2bf(x0.y);
  o[2] = (short)f2bf(x0.z); o[3] = (short)f2bf(x0.w);
  o[4] = (short)f2bf(x1.x); o[5] = (short)f2bf(x1.y);
  o[6] = (short)f2bf(x1.z); o[7] = (short)f2bf(x1.w);
  *reinterpret_cast<bf16x8*>(dst + base) = o;
}

__global__ void zeropad_kernel(unsigned short* __restrict__ H) {
  long long i = (long long)blockIdx.x * blockDim.x + threadIdx.x;
  long long base = (long long)N_NODE * DD + i * 8;
  if (base < (long long)N_PAD * DD) {
    bf16x8 z;
    for (int k = 0; k < 8; ++k) z[k] = 0;
    *reinterpret_cast<bf16x8*>(H + base) = z;
  }
}

// ---- 256x256 GEMM core, BK=32, 4-stage circular LDS, counted vmcnt ---------
// LDS: As/Bs = 4 stages x [256][32] bf16 (linear; BK=32 row stride 64B ->
// ds_read_b128 pattern is naturally bank-conflict-free).
// Pipeline invariant at iter t's wait: outstanding = stages t,t+1,t+2
// (4 gload16 each) -> vmcnt(8) retires stage t (oldest). Each wave confirms
// ITS OWN stage-t loads before s_barrier => after barrier ALL portions landed.
// Stage t+3 (issued after barrier) overwrites slot (t-1)&3, whose readers all
// passed the barrier. Never vmcnt(0) until the last iter (T4).

struct StageSrc { const unsigned short *a0, *a1, *b0, *b1; };

__device__ __forceinline__ void issue_stage(const StageSrc& s, int kelem,
                                            unsigned short* sA, unsigned short* sB,
                                            int wid) {
  unsigned short* dA = sA + wid * 512;   // wave-uniform; HW adds lane*16B
  unsigned short* dB = sB + wid * 512;
  gload16(s.a0 + kelem, dA);
  gload16(s.a1 + kelem, dA + 4096);
  gload16(s.b0 + kelem, dB);
  gload16(s.b1 + kelem, dB + 4096);
}

__device__ __forceinline__ void gemm_core256(
    const StageSrc& s, unsigned short* As, unsigned short* Bs,
    int wid, int rA, int rB, int kq8, f32x4 acc[8][4]) {
  issue_stage(s, 0, As, Bs, wid);
  issue_stage(s, BKT, As + 8192, Bs + 8192, wid);
  issue_stage(s, 2 * BKT, As + 16384, Bs + 16384, wid);
  #pragma unroll
  for (int t = 0; t < NKT; ++t) {
    __builtin_amdgcn_sched_barrier(0);
    if (t < NKT - 2)       asm volatile("s_waitcnt vmcnt(8)" ::: "memory");
    else if (t == NKT - 2) asm volatile("s_waitcnt vmcnt(4)" ::: "memory");
    else                   asm volatile("s_waitcnt vmcnt(0)" ::: "memory");
    __builtin_amdgcn_s_barrier();
    __builtin_amdgcn_sched_barrier(0);
    if (t + 3 < NKT)
      issue_stage(s, (t + 3) * BKT, As + ((t + 3) & 3) * 8192,
                  Bs + ((t + 3) & 3) * 8192, wid);
    const unsigned short* as = As + (t & 3) * 8192;
    const unsigned short* bs = Bs + (t & 3) * 8192;
    bf16x8 a[8], b[4];
    #pragma unroll
    for (int m = 0; m < 8; ++m)
      a[m] = *reinterpret_cast<const bf16x8*>(as + (rA + m * 16) * BKT + kq8);
    #pragma unroll
    for (int n = 0; n < 4; ++n)
      b[n] = *reinterpret_cast<const bf16x8*>(bs + (rB + n * 16) * BKT + kq8);
    __builtin_amdgcn_s_setprio(1);
    #pragma unroll
    for (int m = 0; m < 8; ++m)
      #pragma unroll
      for (int n = 0; n < 4; ++n)
        acc[m][n] = __builtin_amdgcn_mfma_f32_16x16x32_bf16(a[m], b[n], acc[m][n], 0, 0, 0);
    __builtin_amdgcn_s_setprio(0);
  }
}

// ---- FF GEMM: C = [relu](A@W^T + bias [+ C])  (combined l+g grid) ----------

template <int RELU, int CADD>
__global__ __launch_bounds__(512, 2) void gemm_ff256(
    const unsigned short* __restrict__ Al, const unsigned short* __restrict__ Wl,
    const float* __restrict__ biasl, unsigned short* __restrict__ Cl, int nwgL,
    const unsigned short* __restrict__ Ag, const unsigned short* __restrict__ Wg,
    const float* __restrict__ biasg, unsigned short* __restrict__ Cg) {
  __shared__ unsigned short As[4 * 8192];
  __shared__ unsigned short Bs[4 * 8192];
  const int tid = threadIdx.x;
  const int lane = tid & 63, wid = tid >> 6;
  const int wr = wid >> 2, wc = wid & 3;

  int tile = xcd_remap(blockIdx.x, gridDim.x);
  const unsigned short *A, *W;
  const float* bias;
  unsigned short* C;
  long long maxA, maxStore;
  if (tile < nwgL) {
    A = Al; W = Wl; bias = biasl; C = Cl; maxA = N_PAD - 1; maxStore = N_PAD;
  } else {
    tile -= nwgL;
    A = Ag; W = Wg; bias = biasg; C = Cg; maxA = N_GRAPH - 1; maxStore = N_GRAPH;
  }
  const long long brow = (long long)(tile >> 1) * 256;
  const long long bcol = (long long)(tile & 1) * 256;

  const int srow = tid >> 2, sslot = (tid & 3) * 8;
  long long ra0 = brow + srow;        if (ra0 > maxA) ra0 = maxA;
  long long ra1 = brow + 128 + srow;  if (ra1 > maxA) ra1 = maxA;
  StageSrc s;
  s.a0 = A + ra0 * DD + sslot;
  s.a1 = A + ra1 * DD + sslot;
  s.b0 = W + (bcol + srow) * DD + sslot;
  s.b1 = W + (bcol + 128 + srow) * DD + sslot;

  const int rA = wr * 128 + (lane & 15);
  const int rB = wc * 64 + (lane & 15);
  const int kq8 = (lane >> 4) * 8;

  f32x4 acc[8][4];
  f32x4 zero = {0.f, 0.f, 0.f, 0.f};
  #pragma unroll
  for (int m = 0; m < 8; ++m)
    #pragma unroll
    for (int n = 0; n < 4; ++n) acc[m][n] = zero;

  gemm_core256(s, As, Bs, wid, rA, rB, kq8, acc);

  float bv[4];
  #pragma unroll
  for (int n = 0; n < 4; ++n) bv[n] = bias[bcol + wc * 64 + n * 16 + (lane & 15)];

  #pragma unroll
  for (int m = 0; m < 8; ++m) {
    #pragma unroll
    for (int j = 0; j < 4; ++j) {
      const long long rowg = brow + wr * 128 + m * 16 + (lane >> 4) * 4 + j;
      if (rowg < maxStore) {
        #pragma unroll
        for (int n = 0; n < 4; ++n) {
          const long long col = bcol + wc * 64 + n * 16 + (lane & 15);
          float v = acc[m][n][j] + bv[n];
          if constexpr (RELU) v = fmaxf(v, 0.f);
          if constexpr (CADD) v += bf2f(C[rowg * DD + col]);
          C[rowg * DD + col] = f2bf(v);
        }
      }
    }
  }
}

// ---- res GEMM + fused JSD reduction ----------------------------------------
// accum[0] = sum_diag (LN2 - softplus(-v))
// accum[1] = sum_all  (softplus(-v) + v)   (rows < N_PAD only; zero rows -> ln2)
// accum[2] = sum_diag (softplus(-v) + v)

__global__ __launch_bounds__(512, 2) void gemm_jsd256(
    const unsigned short* __restrict__ A, const unsigned short* __restrict__ B,
    const int* __restrict__ batch, double* __restrict__ accum) {
  __shared__ unsigned short As[4 * 8192];
  __shared__ unsigned short Bs[4 * 8192];
  __shared__ int sbatch[256];
  __shared__ float sred[24];
  const int tid = threadIdx.x;
  const int lane = tid & 63, wid = tid >> 6;
  const int wr = wid >> 2, wc = wid & 3;

  const int tile = xcd_remap(blockIdx.x, gridDim.x);
  const long long brow = (long long)(tile >> 2) * 256;
  const long long bcol = (long long)(tile & 3) * 256;

  if (tid < 256) {
    long long gr = brow + tid;
    sbatch[tid] = (gr < N_NODE) ? batch[gr] : -1;
  }

  const int srow = tid >> 2, sslot = (tid & 3) * 8;
  long long ra0 = brow + srow;        if (ra0 > N_PAD - 1) ra0 = N_PAD - 1;
  long long ra1 = brow + 128 + srow;  if (ra1 > N_PAD - 1) ra1 = N_PAD - 1;
  StageSrc s;
  s.a0 = A + ra0 * DD + sslot;
  s.a1 = A + ra1 * DD + sslot;
  s.b0 = B + (bcol + srow) * DD + sslot;
  s.b1 = B + (bcol + 128 + srow) * DD + sslot;

  const int rA = wr * 128 + (lane & 15);
  const int rB = wc * 64 + (lane & 15);
  const int kq8 = (lane >> 4) * 8;

  f32x4 acc[8][4];
  f32x4 zero = {0.f, 0.f, 0.f, 0.f};
  #pragma unroll
  for (int m = 0; m < 8; ++m)
    #pragma unroll
    for (int n = 0; n < 4; ++n) acc[m][n] = zero;

  gemm_core256(s, As, Bs, wid, rA, rB, kq8, acc);

  const float LN2 = 0.69314718055994530942f;
  float sAll = 0.f, sPos = 0.f, sDiag = 0.f;
  #pragma unroll
  for (int m = 0; m < 8; ++m) {
    #pragma unroll
    for (int j = 0; j < 4; ++j) {
      const int lr = wr * 128 + m * 16 + (lane >> 4) * 4 + j;
      const long long rowg = brow + lr;
      if (rowg < N_PAD) {
        const int bg = sbatch[lr];
        #pragma unroll
        for (int n = 0; n < 4; ++n) {
          const int col = (int)bcol + wc * 64 + n * 16 + (lane & 15);
          float v = acc[m][n][j];
          float t = __expf(-fabsf(v));
          float spn = fmaxf(-v, 0.f) + __logf(1.0f + t);   // softplus(-v)
          sAll += spn + v;
          if (col == bg) {
            sPos += LN2 - spn;
            sDiag += spn + v;
          }
        }
      }
    }
  }
  #pragma unroll
  for (int off = 32; off > 0; off >>= 1) {
    sAll  += __shfl_down(sAll, off);
    sPos  += __shfl_down(sPos, off);
    sDiag += __shfl_down(sDiag, off);
  }
  if (lane == 0) { sred[wid] = sPos; sred[8 + wid] = sAll; sred[16 + wid] = sDiag; }
  __syncthreads();
  if (tid == 0) {
    float p = 0.f, a = 0.f, d = 0.f;
    #pragma unroll
    for (int w = 0; w < 8; ++w) { p += sred[w]; a += sred[8 + w]; d += sred[16 + w]; }
    atomicAdd(accum,     (double)p);
    atomicAdd(accum + 1, (double)a);
    atomicAdd(accum + 2, (double)d);
  }
}

__global__ void finalize_kernel(const double* __restrict__ accum,
                                float* __restrict__ out) {
  if (threadIdx.x == 0 && blockIdx.x == 0) {
    const double LN2 = 0.6931471805599453094172321;
    double posSum = accum[0];
    double negSum = (accum[1] - accum[2])
                  - ((double)N_PAD * N_GRAPH - (double)N_NODE) * LN2;
    double Epos = posSum / (double)N_NODE;
    double Eneg = negSum / ((double)N_NODE * (double)(N_GRAPH - 1));
    out[0] = (float)(Eneg - Epos);
  }
}

// ---- launch -----------------------------------------------------------------

extern "C" void kernel_launch(void* const* d_in, const int* in_sizes, int n_in,
                              void* d_out, int out_size, void* d_ws, size_t ws_size,
                              hipStream_t stream) {
  const float* node  = (const float*)d_in[0];
  const float* graph = (const float*)d_in[1];
  const int*   batch = (const int*)d_in[2];
  const float* lw0 = (const float*)d_in[3];
  const float* lb0 = (const float*)d_in[4];
  const float* lw1 = (const float*)d_in[5];
  const float* lb1 = (const float*)d_in[6];
  const float* lw2 = (const float*)d_in[7];
  const float* lb2 = (const float*)d_in[8];
  const float* lws = (const float*)d_in[9];
  const float* lbs = (const float*)d_in[10];
  const float* gw0 = (const float*)d_in[11];
  const float* gb0 = (const float*)d_in[12];
  const float* gw1 = (const float*)d_in[13];
  const float* gb1 = (const float*)d_in[14];
  const float* gw2 = (const float*)d_in[15];
  const float* gb2 = (const float*)d_in[16];
  const float* gws = (const float*)d_in[17];
  const float* gbs = (const float*)d_in[18];

  // workspace layout (identical to R2's known-fitting layout)
  char* ws = (char*)d_ws;
  double*         accum = (double*)ws;                          // 24 B
  unsigned short* WB  = (unsigned short*)(ws + 256);            // 8 x 512x512 bf16
  unsigned short* XB  = (unsigned short*)(ws + 4194560LL);      // [N_PAD,512] bf16
  unsigned short* H1  = (unsigned short*)(ws + 55443712LL);
  unsigned short* H2  = (unsigned short*)(ws + 106692864LL);
  unsigned short* GXB = (unsigned short*)(ws + 157942016LL);
  unsigned short* GH1 = (unsigned short*)(ws + 158990592LL);
  unsigned short* GH2 = (unsigned short*)(ws + 160039168LL);
  if (ws_size < 161087744ULL) return;

  hipMemsetAsync(accum, 0, 32, stream);

  WPtrs wp;
  wp.p[0] = lw0; wp.p[1] = lw1; wp.p[2] = lw2; wp.p[3] = lws;
  wp.p[4] = gw0; wp.p[5] = gw1; wp.p[6] = gw2; wp.p[7] = gws;
  cast_w_kernel<<<1024, 256, 0, stream>>>(wp, WB);
  cast_pad_kernel<<<12512, 256, 0, stream>>>(node, XB, N_NODE, N_PAD);
  cast_pad_kernel<<<256, 256, 0, stream>>>(graph, GXB, N_GRAPH, N_GRAPH);

  dim3 blk(512);
  const int nwgL = 196 * 2;           // l: 196 row-tiles x 2 col-tiles
  const int nwgG = 4 * 2;             // g: 4 row-tiles x 2 col-tiles
  dim3 gff(nwgL + nwgG);
  dim3 gr(196 * 4);                   // jsd: 196 x 4 col-tiles

  gemm_ff256<1, 0><<<gff, blk, 0, stream>>>(
      XB, WB + 0 * 262144, lb0, H1, nwgL,
      GXB, WB + 4 * 262144, gb0, GH1);
  gemm_ff256<1, 0><<<gff, blk, 0, stream>>>(
      H1, WB + 1 * 262144, lb1, H2, nwgL,
      GH1, WB + 5 * 262144, gb1, GH2);
  gemm_ff256<1, 0><<<gff, blk, 0, stream>>>(
      H2, WB + 2 * 262144, lb2, H1, nwgL,
      GH2, WB + 6 * 262144, gb2, GH1);
  gemm_ff256<0, 1><<<gff, blk, 0, stream>>>(
      XB, WB + 3 * 262144, lbs, H1, nwgL,
      GXB, WB + 7 * 262144, gbs, GH1);

  zeropad_kernel<<<12, 256, 0, stream>>>(H1);
  gemm_jsd256<<<gr, blk, 0, stream>>>(H1, GH1, batch, accum);
  finalize_kernel<<<1, 64, 0, stream>>>(accum, (float*)d_out);
}

// Round 5
// 346.609 us; speedup vs baseline: 1.0142x; 1.0142x over previous
//
#include <hip/hip_runtime.h>
#include <hip/hip_bf16.h>

#define N_NODE  50000
#define N_PAD   50048   // buffer row count (391*128); M-tiles of 256 cover 50176 w/ clamp+guard
#define N_GRAPH 1024
#define DD      512
#define BKT     32
#define NKT     16      // 512 / 32

typedef __attribute__((ext_vector_type(8))) short bf16x8;
typedef __attribute__((ext_vector_type(4))) float f32x4;

__device__ __forceinline__ unsigned short f2bf(float f) {
  unsigned int u = __builtin_bit_cast(unsigned int, f);
  return (unsigned short)((u + 0x7FFFu + ((u >> 16) & 1u)) >> 16);  // RTN-even
}

__device__ __forceinline__ float bf2f(unsigned short h) {
  unsigned int u = ((unsigned int)h) << 16;
  return __builtin_bit_cast(float, u);
}

__device__ __forceinline__ void gload16(const void* g, void* l) {
  __builtin_amdgcn_global_load_lds(
      (const __attribute__((address_space(1))) unsigned int*)g,
      (__attribute__((address_space(3))) unsigned int*)l, 16, 0, 0);
}

// T1: bijective XCD-chunk remap (m204 variant)
__device__ __forceinline__ int xcd_remap(int bid, int nwg) {
  int xcd = bid & 7;
  int local = bid >> 3;
  int q = nwg >> 3, r = nwg & 7;
  int base = (xcd < r) ? xcd * (q + 1) : r * (q + 1) + (xcd - r) * q;
  return base + local;
}

// ---- cast kernels -----------------------------------------------------------

__global__ void cast_pad_kernel(const float* __restrict__ src,
                                unsigned short* __restrict__ dst,
                                int srcRows, int dstRows) {
  long long base = ((long long)blockIdx.x * blockDim.x + threadIdx.x) * 8;
  if (base >= (long long)dstRows * DD) return;
  int row = (int)(base >> 9);
  bf16x8 o;
  if (row < srcRows) {
    float4 x0 = reinterpret_cast<const float4*>(src + base)[0];
    float4 x1 = reinterpret_cast<const float4*>(src + base)[1];
    o[0] = (short)f2bf(x0.x); o[1] = (short)f2bf(x0.y);
    o[2] = (short)f2bf(x0.z); o[3] = (short)f2bf(x0.w);
    o[4] = (short)f2bf(x1.x); o[5] = (short)f2bf(x1.y);
    o[6] = (short)f2bf(x1.z); o[7] = (short)f2bf(x1.w);
  } else {
    for (int i = 0; i < 8; ++i) o[i] = 0;
  }
  *reinterpret_cast<bf16x8*>(dst + base) = o;
}

struct WPtrs { const float* p[8]; };

__global__ void cast_w_kernel(WPtrs ps, unsigned short* __restrict__ dst) {
  long long base = ((long long)blockIdx.x * blockDim.x + threadIdx.x) * 8;
  int mat = (int)(base >> 18);
  int off = (int)(base & 262143LL);
  const float* s = ps.p[mat] + off;
  float4 x0 = reinterpret_cast<const float4*>(s)[0];
  float4 x1 = reinterpret_cast<const float4*>(s)[1];
  bf16x8 o;
  o[0] = (short)f2bf(x0.x); o[1] = (short)f2bf(x0.y);
  o[2] = (short)f2bf(x0.z); o[3] = (short)f2bf(x0.w);
  o[4] = (short)f2bf(x1.x); o[5] = (short)f2bf(x1.y);
  o[6] = (short)f2bf(x1.z); o[7] = (short)f2bf(x1.w);
  *reinterpret_cast<bf16x8*>(dst + base) = o;
}

__global__ void zeropad_kernel(unsigned short* __restrict__ H) {
  long long i = (long long)blockIdx.x * blockDim.x + threadIdx.x;
  long long base = (long long)N_NODE * DD + i * 8;
  if (base < (long long)N_PAD * DD) {
    bf16x8 z;
    for (int k = 0; k < 8; ++k) z[k] = 0;
    *reinterpret_cast<bf16x8*>(H + base) = z;
  }
}

// ---- 256x256 GEMM core, BK=32, 4-stage circular LDS, counted vmcnt ---------
// T2 swizzle: LDS [256 rows][4 slots of 16B]; physical slot p of row r holds
// logical K-slot p ^ ((r>>1)&3). Start-bank = 16*(r&1) + 4*p mod 32; over 16
// consecutive rows (r&1, (r>>1)&3) covers all 8 combos twice -> 2 lanes/bank
// = conflict-free. Swizzle term is constant per lane (m*16 ≡ 0 mod (4<<1)),
// so read and staging offsets are precomputed once (zero per-iter VALU).
// global_load_lds writes linearly -> swizzle applied on GLOBAL source (rule 21).
// Pipeline: stages t,t+1,t+2 outstanding at iter t's wait -> vmcnt(8) retires
// stage t. Never vmcnt(0) until the tail (T4).

struct StageSrc { const unsigned short *a0, *a1, *b0, *b1; };

__device__ __forceinline__ void issue_stage(const StageSrc& s, int kelem,
                                            unsigned short* sA, unsigned short* sB,
                                            int wid) {
  unsigned short* dA = sA + wid * 512;   // wave-uniform; HW adds lane*16B
  unsigned short* dB = sB + wid * 512;
  gload16(s.a0 + kelem, dA);
  gload16(s.a1 + kelem, dA + 4096);
  gload16(s.b0 + kelem, dB);
  gload16(s.b1 + kelem, dB + 4096);
}

__device__ __forceinline__ void gemm_core256(
    const StageSrc& s, unsigned short* As, unsigned short* Bs,
    int wid, int rA, int rB, int pa8, int pb8, f32x4 acc[8][4]) {
  issue_stage(s, 0, As, Bs, wid);
  issue_stage(s, BKT, As + 8192, Bs + 8192, wid);
  issue_stage(s, 2 * BKT, As + 16384, Bs + 16384, wid);
  #pragma unroll
  for (int t = 0; t < NKT; ++t) {
    __builtin_amdgcn_sched_barrier(0);
    if (t < NKT - 2)       asm volatile("s_waitcnt vmcnt(8)" ::: "memory");
    else if (t == NKT - 2) asm volatile("s_waitcnt vmcnt(4)" ::: "memory");
    else                   asm volatile("s_waitcnt vmcnt(0)" ::: "memory");
    __builtin_amdgcn_s_barrier();
    __builtin_amdgcn_sched_barrier(0);
    if (t + 3 < NKT)
      issue_stage(s, (t + 3) * BKT, As + ((t + 3) & 3) * 8192,
                  Bs + ((t + 3) & 3) * 8192, wid);
    const unsigned short* as = As + (t & 3) * 8192;
    const unsigned short* bs = Bs + (t & 3) * 8192;
    bf16x8 a[8], b[4];
    #pragma unroll
    for (int m = 0; m < 8; ++m)
      a[m] = *reinterpret_cast<const bf16x8*>(as + (rA + m * 16) * BKT + pa8);
    #pragma unroll
    for (int n = 0; n < 4; ++n)
      b[n] = *reinterpret_cast<const bf16x8*>(bs + (rB + n * 16) * BKT + pb8);
    __builtin_amdgcn_s_setprio(1);
    #pragma unroll
    for (int m = 0; m < 8; ++m)
      #pragma unroll
      for (int n = 0; n < 4; ++n)
        acc[m][n] = __builtin_amdgcn_mfma_f32_16x16x32_bf16(a[m], b[n], acc[m][n], 0, 0, 0);
    __builtin_amdgcn_s_setprio(0);
  }
}

// ---- FF GEMM: C = [relu](A@W^T + bias [+ C])  (combined l+g grid) ----------

template <int RELU, int CADD>
__global__ __launch_bounds__(512, 2) void gemm_ff256(
    const unsigned short* __restrict__ Al, const unsigned short* __restrict__ Wl,
    const float* __restrict__ biasl, unsigned short* __restrict__ Cl, int nwgL,
    const unsigned short* __restrict__ Ag, const unsigned short* __restrict__ Wg,
    const float* __restrict__ biasg, unsigned short* __restrict__ Cg) {
  __shared__ unsigned short As[4 * 8192];
  __shared__ unsigned short Bs[4 * 8192];
  const int tid = threadIdx.x;
  const int lane = tid & 63, wid = tid >> 6;
  const int wr = wid >> 2, wc = wid & 3;

  int tile = xcd_remap(blockIdx.x, gridDim.x);
  const unsigned short *A, *W;
  const float* bias;
  unsigned short* C;
  long long maxA, maxStore;
  if (tile < nwgL) {
    A = Al; W = Wl; bias = biasl; C = Cl; maxA = N_PAD - 1; maxStore = N_PAD;
  } else {
    tile -= nwgL;
    A = Ag; W = Wg; bias = biasg; C = Cg; maxA = N_GRAPH - 1; maxStore = N_GRAPH;
  }
  const long long brow = (long long)(tile >> 1) * 256;
  const long long bcol = (long long)(tile & 1) * 256;

  // staging source: inverse-swizzled slot (T2, rule 21)
  const int srow = tid >> 2;
  const int sslot = (((tid & 3) ^ ((tid >> 3) & 3))) * 8;
  long long ra0 = brow + srow;        if (ra0 > maxA) ra0 = maxA;
  long long ra1 = brow + 128 + srow;  if (ra1 > maxA) ra1 = maxA;
  StageSrc s;
  s.a0 = A + ra0 * DD + sslot;
  s.a1 = A + ra1 * DD + sslot;
  s.b0 = W + (bcol + srow) * DD + sslot;
  s.b1 = W + (bcol + 128 + srow) * DD + sslot;

  const int rA = wr * 128 + (lane & 15);
  const int rB = wc * 64 + (lane & 15);
  const int q = lane >> 4;
  const int pa8 = (q ^ ((rA >> 1) & 3)) * 8;   // swizzled read slot (const/lane)
  const int pb8 = (q ^ ((rB >> 1) & 3)) * 8;

  f32x4 acc[8][4];
  f32x4 zero = {0.f, 0.f, 0.f, 0.f};
  #pragma unroll
  for (int m = 0; m < 8; ++m)
    #pragma unroll
    for (int n = 0; n < 4; ++n) acc[m][n] = zero;

  gemm_core256(s, As, Bs, wid, rA, rB, pa8, pb8, acc);

  float bv[4];
  #pragma unroll
  for (int n = 0; n < 4; ++n) bv[n] = bias[bcol + wc * 64 + n * 16 + (lane & 15)];

  #pragma unroll
  for (int m = 0; m < 8; ++m) {
    #pragma unroll
    for (int j = 0; j < 4; ++j) {
      const long long rowg = brow + wr * 128 + m * 16 + (lane >> 4) * 4 + j;
      if (rowg < maxStore) {
        #pragma unroll
        for (int n = 0; n < 4; ++n) {
          const long long col = bcol + wc * 64 + n * 16 + (lane & 15);
          float v = acc[m][n][j] + bv[n];
          if constexpr (RELU) v = fmaxf(v, 0.f);
          if constexpr (CADD) v += bf2f(C[rowg * DD + col]);
          C[rowg * DD + col] = f2bf(v);
        }
      }
    }
  }
}

// ---- res GEMM + fused JSD reduction ----------------------------------------
// accum[0] = sum_diag (LN2 - softplus(-v))
// accum[1] = sum_all  (softplus(-v) + v)   (rows < N_PAD only; zero rows -> ln2)
// accum[2] = sum_diag (softplus(-v) + v)

__global__ __launch_bounds__(512, 2) void gemm_jsd256(
    const unsigned short* __restrict__ A, const unsigned short* __restrict__ B,
    const int* __restrict__ batch, double* __restrict__ accum) {
  __shared__ unsigned short As[4 * 8192];
  __shared__ unsigned short Bs[4 * 8192];
  __shared__ int sbatch[256];
  __shared__ float sred[24];
  const int tid = threadIdx.x;
  const int lane = tid & 63, wid = tid >> 6;
  const int wr = wid >> 2, wc = wid & 3;

  const int tile = xcd_remap(blockIdx.x, gridDim.x);
  const long long brow = (long long)(tile >> 2) * 256;
  const long long bcol = (long long)(tile & 3) * 256;

  if (tid < 256) {
    long long gr = brow + tid;
    sbatch[tid] = (gr < N_NODE) ? batch[gr] : -1;
  }

  const int srow = tid >> 2;
  const int sslot = (((tid & 3) ^ ((tid >> 3) & 3))) * 8;
  long long ra0 = brow + srow;        if (ra0 > N_PAD - 1) ra0 = N_PAD - 1;
  long long ra1 = brow + 128 + srow;  if (ra1 > N_PAD - 1) ra1 = N_PAD - 1;
  StageSrc s;
  s.a0 = A + ra0 * DD + sslot;
  s.a1 = A + ra1 * DD + sslot;
  s.b0 = B + (bcol + srow) * DD + sslot;
  s.b1 = B + (bcol + 128 + srow) * DD + sslot;

  const int rA = wr * 128 + (lane & 15);
  const int rB = wc * 64 + (lane & 15);
  const int q = lane >> 4;
  const int pa8 = (q ^ ((rA >> 1) & 3)) * 8;
  const int pb8 = (q ^ ((rB >> 1) & 3)) * 8;

  f32x4 acc[8][4];
  f32x4 zero = {0.f, 0.f, 0.f, 0.f};
  #pragma unroll
  for (int m = 0; m < 8; ++m)
    #pragma unroll
    for (int n = 0; n < 4; ++n) acc[m][n] = zero;

  gemm_core256(s, As, Bs, wid, rA, rB, pa8, pb8, acc);

  const float LN2 = 0.69314718055994530942f;
  float sAll = 0.f, sPos = 0.f, sDiag = 0.f;
  #pragma unroll
  for (int m = 0; m < 8; ++m) {
    #pragma unroll
    for (int j = 0; j < 4; ++j) {
      const int lr = wr * 128 + m * 16 + (lane >> 4) * 4 + j;
      const long long rowg = brow + lr;
      if (rowg < N_PAD) {
        const int bg = sbatch[lr];
        #pragma unroll
        for (int n = 0; n < 4; ++n) {
          const int col = (int)bcol + wc * 64 + n * 16 + (lane & 15);
          float v = acc[m][n][j];
          float t = __expf(-fabsf(v));
          float spn = fmaxf(-v, 0.f) + __logf(1.0f + t);   // softplus(-v)
          sAll += spn + v;
          if (col == bg) {
            sPos += LN2 - spn;
            sDiag += spn + v;
          }
        }
      }
    }
  }
  #pragma unroll
  for (int off = 32; off > 0; off >>= 1) {
    sAll  += __shfl_down(sAll, off);
    sPos  += __shfl_down(sPos, off);
    sDiag += __shfl_down(sDiag, off);
  }
  if (lane == 0) { sred[wid] = sPos; sred[8 + wid] = sAll; sred[16 + wid] = sDiag; }
  __syncthreads();
  if (tid == 0) {
    float p = 0.f, a = 0.f, d = 0.f;
    #pragma unroll
    for (int w = 0; w < 8; ++w) { p += sred[w]; a += sred[8 + w]; d += sred[16 + w]; }
    atomicAdd(accum,     (double)p);
    atomicAdd(accum + 1, (double)a);
    atomicAdd(accum + 2, (double)d);
  }
}

__global__ void finalize_kernel(const double* __restrict__ accum,
                                float* __restrict__ out) {
  if (threadIdx.x == 0 && blockIdx.x == 0) {
    const double LN2 = 0.6931471805599453094172321;
    double posSum = accum[0];
    double negSum = (accum[1] - accum[2])
                  - ((double)N_PAD * N_GRAPH - (double)N_NODE) * LN2;
    double Epos = posSum / (double)N_NODE;
    double Eneg = negSum / ((double)N_NODE * (double)(N_GRAPH - 1));
    out[0] = (float)(Eneg - Epos);
  }
}

// ---- launch -----------------------------------------------------------------

extern "C" void kernel_launch(void* const* d_in, const int* in_sizes, int n_in,
                              void* d_out, int out_size, void* d_ws, size_t ws_size,
                              hipStream_t stream) {
  const float* node  = (const float*)d_in[0];
  const float* graph = (const float*)d_in[1];
  const int*   batch = (const int*)d_in[2];
  const float* lw0 = (const float*)d_in[3];
  const float* lb0 = (const float*)d_in[4];
  const float* lw1 = (const float*)d_in[5];
  const float* lb1 = (const float*)d_in[6];
  const float* lw2 = (const float*)d_in[7];
  const float* lb2 = (const float*)d_in[8];
  const float* lws = (const float*)d_in[9];
  const float* lbs = (const float*)d_in[10];
  const float* gw0 = (const float*)d_in[11];
  const float* gb0 = (const float*)d_in[12];
  const float* gw1 = (const float*)d_in[13];
  const float* gb1 = (const float*)d_in[14];
  const float* gw2 = (const float*)d_in[15];
  const float* gb2 = (const float*)d_in[16];
  const float* gws = (const float*)d_in[17];
  const float* gbs = (const float*)d_in[18];

  // workspace layout (identical to R2/R3's known-fitting layout)
  char* ws = (char*)d_ws;
  double*         accum = (double*)ws;                          // 24 B
  unsigned short* WB  = (unsigned short*)(ws + 256);            // 8 x 512x512 bf16
  unsigned short* XB  = (unsigned short*)(ws + 4194560LL);      // [N_PAD,512] bf16
  unsigned short* H1  = (unsigned short*)(ws + 55443712LL);
  unsigned short* H2  = (unsigned short*)(ws + 106692864LL);
  unsigned short* GXB = (unsigned short*)(ws + 157942016LL);
  unsigned short* GH1 = (unsigned short*)(ws + 158990592LL);
  unsigned short* GH2 = (unsigned short*)(ws + 160039168LL);
  if (ws_size < 161087744ULL) return;

  hipMemsetAsync(accum, 0, 32, stream);

  WPtrs wp;
  wp.p[0] = lw0; wp.p[1] = lw1; wp.p[2] = lw2; wp.p[3] = lws;
  wp.p[4] = gw0; wp.p[5] = gw1; wp.p[6] = gw2; wp.p[7] = gws;
  cast_w_kernel<<<1024, 256, 0, stream>>>(wp, WB);
  cast_pad_kernel<<<12512, 256, 0, stream>>>(node, XB, N_NODE, N_PAD);
  cast_pad_kernel<<<256, 256, 0, stream>>>(graph, GXB, N_GRAPH, N_GRAPH);

  dim3 blk(512);
  const int nwgL = 196 * 2;           // l: 196 row-tiles x 2 col-tiles
  const int nwgG = 4 * 2;             // g: 4 row-tiles x 2 col-tiles
  dim3 gff(nwgL + nwgG);
  dim3 gr(196 * 4);                   // jsd: 196 x 4 col-tiles

  gemm_ff256<1, 0><<<gff, blk, 0, stream>>>(
      XB, WB + 0 * 262144, lb0, H1, nwgL,
      GXB, WB + 4 * 262144, gb0, GH1);
  gemm_ff256<1, 0><<<gff, blk, 0, stream>>>(
      H1, WB + 1 * 262144, lb1, H2, nwgL,
      GH1, WB + 5 * 262144, gb1, GH2);
  gemm_ff256<1, 0><<<gff, blk, 0, stream>>>(
      H2, WB + 2 * 262144, lb2, H1, nwgL,
      GH2, WB + 6 * 262144, gb2, GH1);
  gemm_ff256<0, 1><<<gff, blk, 0, stream>>>(
      XB, WB + 3 * 262144, lbs, H1, nwgL,
      GXB, WB + 7 * 262144, gbs, GH1);

  zeropad_kernel<<<12, 256, 0, stream>>>(H1);
  gemm_jsd256<<<gr, blk, 0, stream>>>(H1, GH1, batch, accum);
  finalize_kernel<<<1, 64, 0, stream>>>(accum, (float*)d_out);
}